// Round 3
// baseline (281.462 us; speedup 1.0000x reference)
//
#include <hip/hip_runtime.h>

#define N_TOK   524288
#define KC      256
#define D       32
#define EPSF    1e-6f
#define NBLK    2048               // 1 thread per token: 2048 x 256 = 524288
#define BLKT    256

// ---------------- main kernel: one token per lane, codebook via SGPRs ----------------
__global__ __launch_bounds__(BLKT, 4) void vq_main(
    const float* __restrict__ x, const float* __restrict__ cb,
    float* __restrict__ out_rot, float* __restrict__ out_idx,
    float* __restrict__ ws_hist, float* __restrict__ out_cnt, int use_ws)
{
    __shared__ float c2s[KC];      // ||c||^2, numpy pairwise order (1 KB)
    __shared__ float hist[KC];     // per-block histogram (1 KB)

    const int tid = threadIdx.x;

    // ---- c2 per code (exact pairwise order, no contraction), zero hist ----
    {
#pragma clang fp contract(off)
        const float4* cb4 = (const float4*)(cb + (size_t)tid * D);
        float4 r[8];
#pragma unroll
        for (int j = 0; j < 8; j++) r[j] = cb4[j];
        float t[32];
#pragma unroll
        for (int j = 0; j < 8; j++) {
            t[4 * j + 0] = r[j].x * r[j].x;
            t[4 * j + 1] = r[j].y * r[j].y;
            t[4 * j + 2] = r[j].z * r[j].z;
            t[4 * j + 3] = r[j].w * r[j].w;
        }
        float pr[8];
#pragma unroll
        for (int j = 0; j < 8; j++)
            pr[j] = ((t[j] + t[j + 8]) + t[j + 16]) + t[j + 24];
        c2s[tid] = ((pr[0] + pr[1]) + (pr[2] + pr[3])) + ((pr[4] + pr[5]) + (pr[6] + pr[7]));
        hist[tid] = 0.f;
    }
    __syncthreads();

    const size_t tok = (size_t)blockIdx.x * BLKT + tid;

    // ---- this lane's token: 32 floats in VGPRs ----
    float xr[32];
    {
        const float4* xg = (const float4*)(x + tok * D);
#pragma unroll
        for (int j = 0; j < 8; j++) {
            float4 v = xg[j];
            xr[4 * j + 0] = v.x; xr[4 * j + 1] = v.y;
            xr[4 * j + 2] = v.z; xr[4 * j + 3] = v.w;
        }
    }

    // ---- ||x||^2, exact numpy pairwise order (no contraction) ----
    float x2v;
    {
#pragma clang fp contract(off)
        float t[32];
#pragma unroll
        for (int k = 0; k < 32; k++) t[k] = xr[k] * xr[k];
        float pr[8];
#pragma unroll
        for (int j = 0; j < 8; j++)
            pr[j] = ((t[j] + t[j + 8]) + t[j + 16]) + t[j + 24];
        x2v = ((pr[0] + pr[1]) + (pr[2] + pr[3])) + ((pr[4] + pr[5]) + (pr[6] + pr[7]));
    }

    // ---- argmin scan over all 256 codes ----
    // cb row address is wave-uniform -> scalar loads (SGPR), v_fmac v,s,v in the chain.
    // Per (token,code): same ascending-k fmaf chain and fl(fl(x2-2acc)+c2) as before;
    // ascending c with strict < == numpy first-min tie-break.
    float bestv = 3.4e38f;
    int   besti = 0x7fffffff;
#pragma unroll 2
    for (int c = 0; c < KC; ++c) {
        const float4* cr = (const float4*)(cb + (size_t)c * D);   // uniform
        const float4 q0 = cr[0], q1 = cr[1], q2 = cr[2], q3 = cr[3];
        const float4 q4 = cr[4], q5 = cr[5], q6 = cr[6], q7 = cr[7];
        const float cs[32] = {q0.x, q0.y, q0.z, q0.w, q1.x, q1.y, q1.z, q1.w,
                              q2.x, q2.y, q2.z, q2.w, q3.x, q3.y, q3.z, q3.w,
                              q4.x, q4.y, q4.z, q4.w, q5.x, q5.y, q5.z, q5.w,
                              q6.x, q6.y, q6.z, q6.w, q7.x, q7.y, q7.z, q7.w};
        float acc = 0.f;
#pragma unroll
        for (int k = 0; k < 32; ++k) acc = __builtin_fmaf(xr[k], cs[k], acc);
        const float t2 = x2v - 2.0f * acc;      // 2*acc exact -> contraction-safe
        const float s  = t2 + c2s[c];           // uniform LDS broadcast read
        if (s < bestv) { bestv = s; besti = c; }
    }

    // ---- rotation epilogue: fully lane-local ----
    float cs[32];
    {
        const float4* cg = (const float4*)(cb + (size_t)besti * D);  // divergent gather, L1-hot
#pragma unroll
        for (int j = 0; j < 8; j++) {
            float4 v = cg[j];
            cs[4 * j + 0] = v.x; cs[4 * j + 1] = v.y;
            cs[4 * j + 2] = v.z; cs[4 * j + 3] = v.w;
        }
    }

    float px2 = 0.f, pc2 = 0.f;
#pragma unroll
    for (int j = 0; j < 32; j++) {
        px2 = fmaf(xr[j], xr[j], px2);
        pc2 = fmaf(cs[j], cs[j], pc2);
    }
    const float inx = 1.f / fmaxf(sqrtf(px2), EPSF);
    const float inc = 1.f / fmaxf(sqrtf(pc2), EPSF);

    float pw2 = 0.f;
#pragma unroll
    for (int j = 0; j < 32; j++) {
        const float wj = xr[j] * inx + cs[j] * inc;
        pw2 = fmaf(wj, wj, pw2);
    }
    const float inw = 1.f / fmaxf(sqrtf(pw2), EPSF);

    float pew = 0.f, peu = 0.f;
#pragma unroll
    for (int j = 0; j < 32; j++) {
        const float uj = xr[j] * inx;
        const float wj = (uj + cs[j] * inc) * inw;
        pew = fmaf(xr[j], wj, pew);
        peu = fmaf(xr[j], uj, peu);
    }
    const float ew = pew, eu = peu;

    {
        float4* og = (float4*)(out_rot + tok * D);
#pragma unroll
        for (int j = 0; j < 8; j++) {
            float r4[4];
#pragma unroll
            for (int e = 0; e < 4; e++) {
                const int jj = 4 * j + e;
                const float uj = xr[jj] * inx;
                const float wj = (uj + cs[jj] * inc) * inw;
                const float qj = cs[jj] * inc;
                r4[e] = xr[jj] - 2.f * ew * wj + 2.f * eu * qj;
            }
            og[j] = make_float4(r4[0], r4[1], r4[2], r4[3]);
        }
    }

    out_idx[tok] = (float)besti;
    atomicAdd(&hist[besti], 1.f);
    __syncthreads();

    // ---- flush per-block histogram ----
    if (use_ws) ws_hist[(size_t)blockIdx.x * KC + tid] = hist[tid];
    else        atomicAdd(&out_cnt[tid], hist[tid]);
}

// ---------------- tiny reduce: 2048 block-partials -> 256 counts ----------------
__global__ __launch_bounds__(256) void vq_reduce(const float* __restrict__ ws,
                                                 float* __restrict__ out_cnt)
{
    const int c = blockIdx.x * 8 + (threadIdx.x >> 5);  // code
    const int l = threadIdx.x & 31;                     // lane within code-group
    float s = 0.f;
    for (int b = l; b < NBLK; b += 32) s += ws[(size_t)b * KC + c];
#pragma unroll
    for (int m = 1; m < 32; m <<= 1) s += __shfl_xor(s, m, 64);
    if (l == 0) out_cnt[c] = s;
}

extern "C" void kernel_launch(void* const* d_in, const int* in_sizes, int n_in,
                              void* d_out, int out_size, void* d_ws, size_t ws_size,
                              hipStream_t stream)
{
    const float* x  = (const float*)d_in[0];
    const float* cb = (const float*)d_in[1];
    float* out      = (float*)d_out;
    float* out_rot  = out;                                   // [524288*32]
    float* out_idx  = out + (size_t)N_TOK * D;               // [524288] (indices as float)
    float* out_cnt  = out_idx + N_TOK;                       // [256]

    const size_t ws_need = (size_t)NBLK * KC * sizeof(float);
    const int use_ws = (ws_size >= ws_need) ? 1 : 0;
    if (!use_ws) hipMemsetAsync(out_cnt, 0, KC * sizeof(float), stream);

    vq_main<<<NBLK, BLKT, 0, stream>>>(x, cb, out_rot, out_idx,
                                       (float*)d_ws, out_cnt, use_ws);
    if (use_ws) vq_reduce<<<32, 256, 0, stream>>>((const float*)d_ws, out_cnt);
}